// Round 1
// baseline (701.117 us; speedup 1.0000x reference)
//
#include <hip/hip_runtime.h>
#include <hip/hip_bf16.h>

typedef __bf16 bf16x8 __attribute__((ext_vector_type(8)));
typedef __bf16 bf16x4 __attribute__((ext_vector_type(4)));
typedef float  f32x4  __attribute__((ext_vector_type(4)));

#define B_    64
#define CIN   64
#define HIN   64
#define WIN   64
#define COUT  128
#define HO    62
#define WO    62
#define NPIX  (B_*HO*WO)        /* 246016 = 1922*128 exactly */
#define NITER 24                /* LDS rounds; +1 final matvec = 25 total */

// ---------------------------------------------------------------------------
// prep_w: W_ff (128,64,3,3) fp32 -> wt[tap][o][c] bf16 ; W_rec -> wr[o][c] bf16
// ---------------------------------------------------------------------------
__global__ void prep_w_kernel(const float* __restrict__ wff,
                              const float* __restrict__ wrec,
                              __bf16* __restrict__ wt,
                              __bf16* __restrict__ wr) {
  int i = blockIdx.x * 256 + threadIdx.x;
  const int NW = 9 * COUT * CIN;            // 73728
  if (i < NW) {
    int tap = i / (COUT * CIN);
    int rem = i % (COUT * CIN);
    int o = rem >> 6;                       // /CIN
    int c = rem & 63;
    int kh = tap / 3, kw = tap % 3;
    wt[i] = (__bf16)wff[((o * CIN + c) * 3 + kh) * 3 + kw];
  } else {
    int j = i - NW;
    if (j < COUT * COUT) wr[j] = (__bf16)wrec[j];
  }
}

// ---------------------------------------------------------------------------
// prep_x: x NCHW fp32 -> NHWC bf16 hi/lo split. One block per (b,h) row.
// ---------------------------------------------------------------------------
__global__ void prep_x_kernel(const float* __restrict__ x,
                              __bf16* __restrict__ xh,
                              __bf16* __restrict__ xl) {
  __shared__ float t[64][65];               // pad -> conflict-free transpose
  int tid = threadIdx.x;
  int b = blockIdx.x >> 6;
  int h = blockIdx.x & 63;
#pragma unroll
  for (int it = 0; it < 16; ++it) {         // read coalesced over w
    int c = it * 4 + (tid >> 6);
    int w = tid & 63;
    t[c][w] = x[(((size_t)(b * 64 + c)) * 64 + h) * 64 + w];
  }
  __syncthreads();
#pragma unroll
  for (int it = 0; it < 16; ++it) {         // write coalesced over c
    int w = it * 4 + (tid >> 6);
    int c = tid & 63;
    float v = t[c][w];
    __bf16 hi = (__bf16)v;
    __bf16 lo = (__bf16)(v - (float)hi);
    size_t o = ((size_t)blockIdx.x * 64 + w) * 64 + c;  // ((b*64+h)*64+w)*64+c
    xh[o] = hi;
    xl[o] = lo;
  }
}

// ---------------------------------------------------------------------------
// conv: tap-decomposed implicit GEMM, bf16 MFMA, x hi/lo split (fp32-grade).
// One block per (h_out, b). 4 waves, each: M=128 (c_out) x N=16 pixels.
// u0 written NHWC fp32 (so iterate's C-layout frag loads are contiguous).
// ---------------------------------------------------------------------------
__global__ __launch_bounds__(256, 2) void conv_kernel(
    const __bf16* __restrict__ xh, const __bf16* __restrict__ xl,
    const __bf16* __restrict__ wt, float* __restrict__ u0) {
  int ho = blockIdx.x;                      // 0..61
  int b  = blockIdx.y;                      // 0..63
  // padded c-stride 72 el = 144 B (mult of 16 -> aligned b128; 2-way banks = free)
  __shared__ __align__(16) __bf16 xs_h[3][64][72];
  __shared__ __align__(16) __bf16 xs_l[3][64][72];
  int tid = threadIdx.x;
  // stage 3 input rows (h=ho..ho+2), all 64 w, all 64 c: 1536 16B-chunks
#pragma unroll
  for (int it = 0; it < 6; ++it) {
    int idx = it * 256 + tid;
    int kh = idx >> 9;
    int w  = (idx >> 3) & 63;
    int cq = idx & 7;
    size_t g = (((size_t)(b * 64 + ho + kh)) * 64 + w) * 64 + cq * 8;
    *(bf16x8*)&xs_h[kh][w][cq * 8] = *(const bf16x8*)&xh[g];
    *(bf16x8*)&xs_l[kh][w][cq * 8] = *(const bf16x8*)&xl[g];
  }
  __syncthreads();

  int lane = tid & 63;
  int wv   = tid >> 6;                      // 0..3: pixel-tile of this wave
  int l15  = lane & 15;
  int quad = lane >> 4;
  int n = wv * 16 + l15;                    // output col; n>=62 discarded

  f32x4 acc[8];
#pragma unroll
  for (int mt = 0; mt < 8; ++mt) acc[mt] = (f32x4){0.f, 0.f, 0.f, 0.f};

  for (int tap = 0; tap < 9; ++tap) {
    int kh = tap / 3, kw = tap % 3;
    int wcol = n + kw;
    if (wcol > 63) wcol = 63;               // garbage for n>=62, discarded
#pragma unroll
    for (int kt = 0; kt < 2; ++kt) {
      int k0 = kt * 32 + quad * 8;
      bf16x8 bh = *(const bf16x8*)&xs_h[kh][wcol][k0];
      bf16x8 bl = *(const bf16x8*)&xs_l[kh][wcol][k0];
      const __bf16* wbase = wt + (size_t)tap * COUT * CIN + k0;
#pragma unroll
      for (int mt = 0; mt < 8; ++mt) {
        int m = mt * 16 + l15;
        bf16x8 af = *(const bf16x8*)&wbase[m * CIN];
        acc[mt] = __builtin_amdgcn_mfma_f32_16x16x32_bf16(af, bh, acc[mt], 0, 0, 0);
        acc[mt] = __builtin_amdgcn_mfma_f32_16x16x32_bf16(af, bl, acc[mt], 0, 0, 0);
      }
    }
  }
  if (n < 62) {
    size_t p = ((size_t)b * HO + ho) * WO + n;
    float* up = u0 + p * COUT + quad * 4;   // C-frag rows: mt*16+quad*4+r
#pragma unroll
    for (int mt = 0; mt < 8; ++mt) *(f32x4*)&up[mt * 16] = acc[mt];
  }
}

// ---------------------------------------------------------------------------
// iterate: 25 undamped Picard steps, fully on-chip.
//   a_{k+1} = relu((u0 - thr) - Wr * a_k),  a_0 = relu(u0 - thr)
// 512 threads = 8 waves; wave owns M=128 (all channels) x N=16 pixels.
// Wr A-frags live in 128 VGPRs; only a (bf16) round-trips through LDS.
// No barriers: each wave reads/writes only its own 16 LDS rows (same-wave
// DS ordering is in-order).
// ---------------------------------------------------------------------------
__global__ __launch_bounds__(512, 2) void iterate_kernel(
    const float* __restrict__ u0, const __bf16* __restrict__ wr,
    const float* __restrict__ thr, float* __restrict__ out) {
  // padded channel-stride 136 el = 272 B (mult of 16; 2-way banks = free)
  __shared__ __align__(16) __bf16 a_s[128][136];
  int tid = threadIdx.x;
  int lane = tid & 63, wv = tid >> 6;
  int l15 = lane & 15, quad = lane >> 4;
  int nloc = wv * 16 + l15;                 // this lane's pixel (col)
  size_t p = (size_t)blockIdx.x * 128 + nloc;
  int pb = (int)(p / (HO * WO));            // batch  (for NCHW store)
  int pr = (int)(p % (HO * WO));            // h*62+w

  // Wr A-fragments (held in registers for the whole kernel): 8 mt x 4 kt
  bf16x8 Af[8][4];
#pragma unroll
  for (int mt = 0; mt < 8; ++mt) {
    int m = mt * 16 + l15;
#pragma unroll
    for (int kt = 0; kt < 4; ++kt)
      Af[mt][kt] = *(const bf16x8*)&wr[(size_t)m * COUT + kt * 32 + quad * 8];
  }
  // u0 fragments (C-layout), threshold folded in once
  f32x4 u0f[8];
#pragma unroll
  for (int mt = 0; mt < 8; ++mt) {
    f32x4 u = *(const f32x4*)&u0[p * COUT + mt * 16 + quad * 4];
    f32x4 t = *(const f32x4*)&thr[mt * 16 + quad * 4];
    u0f[mt] = u - t;
  }
  // a_0 = relu(u0 - thr) -> LDS (bf16), C-layout positions
#pragma unroll
  for (int mt = 0; mt < 8; ++mt) {
    bf16x4 pk;
    pk[0] = (__bf16)fmaxf(u0f[mt][0], 0.f);
    pk[1] = (__bf16)fmaxf(u0f[mt][1], 0.f);
    pk[2] = (__bf16)fmaxf(u0f[mt][2], 0.f);
    pk[3] = (__bf16)fmaxf(u0f[mt][3], 0.f);
    *(bf16x4*)&a_s[nloc][mt * 16 + quad * 4] = pk;
  }
#pragma unroll 1
  for (int it = 0; it < NITER; ++it) {
    bf16x8 Bf[4];
#pragma unroll
    for (int kt = 0; kt < 4; ++kt)
      Bf[kt] = *(const bf16x8*)&a_s[nloc][kt * 32 + quad * 8];
#pragma unroll
    for (int mt = 0; mt < 8; ++mt) {
      f32x4 acc = (f32x4){0.f, 0.f, 0.f, 0.f};
#pragma unroll
      for (int kt = 0; kt < 4; ++kt)
        acc = __builtin_amdgcn_mfma_f32_16x16x32_bf16(Af[mt][kt], Bf[kt], acc, 0, 0, 0);
      f32x4 a = u0f[mt] - acc;
      bf16x4 pk;
      pk[0] = (__bf16)fmaxf(a[0], 0.f);
      pk[1] = (__bf16)fmaxf(a[1], 0.f);
      pk[2] = (__bf16)fmaxf(a[2], 0.f);
      pk[3] = (__bf16)fmaxf(a[3], 0.f);
      *(bf16x4*)&a_s[nloc][mt * 16 + quad * 4] = pk;
    }
  }
  // final matvec -> a (fp32) -> NCHW global store
  {
    bf16x8 Bf[4];
#pragma unroll
    for (int kt = 0; kt < 4; ++kt)
      Bf[kt] = *(const bf16x8*)&a_s[nloc][kt * 32 + quad * 8];
#pragma unroll
    for (int mt = 0; mt < 8; ++mt) {
      f32x4 acc = (f32x4){0.f, 0.f, 0.f, 0.f};
#pragma unroll
      for (int kt = 0; kt < 4; ++kt)
        acc = __builtin_amdgcn_mfma_f32_16x16x32_bf16(Af[mt][kt], Bf[kt], acc, 0, 0, 0);
      f32x4 a = u0f[mt] - acc;
#pragma unroll
      for (int r = 0; r < 4; ++r) {
        size_t ob = ((size_t)pb * COUT + mt * 16 + quad * 4 + r) * (HO * WO) + pr;
        out[ob] = fmaxf(a[r], 0.f);
      }
    }
  }
}

// ---------------------------------------------------------------------------
extern "C" void kernel_launch(void* const* d_in, const int* in_sizes, int n_in,
                              void* d_out, int out_size, void* d_ws, size_t ws_size,
                              hipStream_t stream) {
  const float* x    = (const float*)d_in[0];   // (64,64,64,64)
  const float* wff  = (const float*)d_in[1];   // (128,64,3,3)
  const float* wrec = (const float*)d_in[2];   // (128,128,1,1)
  const float* thr  = (const float*)d_in[3];   // (128,)
  float* out = (float*)d_out;                  // (64,128,62,62)

  char* ws = (char*)d_ws;
  size_t off = 0;
  float*  u0 = (float*)(ws + off);  off += (size_t)NPIX * COUT * 4;          // 126 MB
  __bf16* xh = (__bf16*)(ws + off); off += (size_t)B_ * HIN * WIN * CIN * 2; // 33.6 MB
  __bf16* xl = (__bf16*)(ws + off); off += (size_t)B_ * HIN * WIN * CIN * 2; // 33.6 MB
  __bf16* wt = (__bf16*)(ws + off); off += (size_t)9 * COUT * CIN * 2;       // 147 KB
  __bf16* wr = (__bf16*)(ws + off); off += (size_t)COUT * COUT * 2;          // 32 KB
  // total ~193 MB; assumed <= ws_size

  prep_w_kernel<<<352, 256, 0, stream>>>(wff, wrec, wt, wr);
  prep_x_kernel<<<B_ * HIN, 256, 0, stream>>>(x, xh, xl);
  conv_kernel<<<dim3(HO, B_), 256, 0, stream>>>(xh, xl, wt, u0);
  iterate_kernel<<<NPIX / 128, 512, 0, stream>>>(u0, wr, thr, out);
}

// Round 2
// 388.870 us; speedup vs baseline: 1.8030x; 1.8030x over previous
//
#include <hip/hip_runtime.h>
#include <hip/hip_bf16.h>

typedef __bf16 bf16x8 __attribute__((ext_vector_type(8)));
typedef __bf16 bf16x4 __attribute__((ext_vector_type(4)));
typedef float  f32x4  __attribute__((ext_vector_type(4)));
typedef float  f32x16 __attribute__((ext_vector_type(16)));

#define B_    64
#define CIN   64
#define HIN   64
#define WIN   64
#define COUT  128
#define HO    62
#define WO    62
#define NPIX  (B_*HO*WO)        /* 246016 = 1922*128 exactly */
#define NITER 13                /* LDS rounds; +1 final matvec = 14 total
                                   contraction rho~0.65 -> 0.65^14*0.6 ~ 1.4e-3 */

// ---------------------------------------------------------------------------
// prep_w: W_ff (128,64,3,3) fp32 -> wt[tap][o][c] bf16 ; W_rec -> wr[o][c] bf16
// ---------------------------------------------------------------------------
__global__ void prep_w_kernel(const float* __restrict__ wff,
                              const float* __restrict__ wrec,
                              __bf16* __restrict__ wt,
                              __bf16* __restrict__ wr) {
  int i = blockIdx.x * 256 + threadIdx.x;
  const int NW = 9 * COUT * CIN;            // 73728
  if (i < NW) {
    int tap = i / (COUT * CIN);
    int rem = i % (COUT * CIN);
    int o = rem >> 6;                       // /CIN
    int c = rem & 63;
    int kh = tap / 3, kw = tap % 3;
    wt[i] = (__bf16)wff[((o * CIN + c) * 3 + kh) * 3 + kw];
  } else {
    int j = i - NW;
    if (j < COUT * COUT) wr[j] = (__bf16)wrec[j];
  }
}

// ---------------------------------------------------------------------------
// prep_x: x NCHW fp32 -> bf16, layout [b][h][c>>3][w][c&7]
// (so conv staging is a flat contiguous 8KB row -> global_load_lds-able,
//  and B-frag ds_read_b128 is lane-contiguous = peak LDS rate).
// One block per (b,h) row.
// ---------------------------------------------------------------------------
__global__ void prep_x_kernel(const float* __restrict__ x,
                              __bf16* __restrict__ xh) {
  __shared__ float t[64][65];               // pad -> conflict-free transpose
  int tid = threadIdx.x;
  int b = blockIdx.x >> 6;
  int h = blockIdx.x & 63;
#pragma unroll
  for (int it = 0; it < 16; ++it) {         // read coalesced over w
    int c = it * 4 + (tid >> 6);
    int w = tid & 63;
    t[c][w] = x[(((size_t)(b * 64 + c)) * 64 + h) * 64 + w];
  }
  __syncthreads();
  size_t rowbase = (size_t)blockIdx.x * 4096;
#pragma unroll
  for (int it = 0; it < 16; ++it) {         // write contiguous
    int j = it * 256 + tid;                 // 0..4095
    int c8  = j & 7;
    int w   = (j >> 3) & 63;
    int grp = j >> 9;
    xh[rowbase + j] = (__bf16)t[grp * 8 + c8][w];
  }
}

// ---------------------------------------------------------------------------
// conv v2: persistent-weight implicit GEMM, 32x32x16 bf16 MFMA.
// Block = (hgroup, b): 4 output rows x 62 px = 248 px (8 n-tiles of 32).
// 4 waves; wave wv owns c_out slice [wv*32, wv*32+32) and holds ALL its
// weights (9 taps x 4 ktiles = 36 bf16x8 frags = 144 VGPRs) in registers.
// x rows staged in LDS via global_load_lds (16B); B-frags are
// lane-contiguous ds_read_b128. Weight traffic ~ 0.
// u0 written NHWC fp32.
// ---------------------------------------------------------------------------
__global__ __launch_bounds__(256, 2) void conv_kernel(
    const __bf16* __restrict__ xh, const __bf16* __restrict__ wt,
    float* __restrict__ u0) {
  // layout [row 6][grp 8][w 64][c8 8] = 24576 el = 48KB, flat == global row order
  __shared__ __align__(16) __bf16 xs[6 * 8 * 64 * 8];
  int tid  = threadIdx.x;
  int lane = tid & 63;
  int wv   = tid >> 6;                      // 0..3 : c_out slice
  int hg   = blockIdx.x;                    // 0..15 : output-row group (4 rows)
  int b    = blockIdx.y;

  // ---- stage 6 input rows (hg*4 .. hg*4+5, clamped) : 48 x 1KB chunks ----
#pragma unroll
  for (int i = 0; i < 12; ++i) {
    int chunk = wv * 12 + i;                // 0..47
    int row = chunk >> 3;                   // local row 0..5
    int part = chunk & 7;                   // 1KB part within 8KB row
    int row_src = hg * 4 + row;
    if (row_src > 63) row_src = 63;         // hg=15 halo clamp (unused outputs)
    const __bf16* g = xh + ((size_t)(b * 64 + row_src)) * 4096 + part * 512 + lane * 8;
    __bf16* l = xs + chunk * 512;           // HW adds lane*16 bytes
    __builtin_amdgcn_global_load_lds(
        (const __attribute__((address_space(1))) void*)g,
        (__attribute__((address_space(3))) void*)l, 16, 0, 0);
  }

  // ---- load this wave's full weight set into registers (L2-hot, once) ----
  int m31 = lane & 31;
  int khalf = lane >> 5;                    // A[m][k]: m=lane&31, k=khalf*8+j
  bf16x8 Wf[36];
#pragma unroll
  for (int tap = 0; tap < 9; ++tap)
#pragma unroll
    for (int k4 = 0; k4 < 4; ++k4)
      Wf[tap * 4 + k4] = *(const bf16x8*)
          &wt[((size_t)tap * COUT + wv * 32 + m31) * CIN + k4 * 16 + khalf * 8];

  __syncthreads();

  // ---- 8 n-tiles of 32 pixels ----
#pragma unroll 1
  for (int nt = 0; nt < 8; ++nt) {
    int px = nt * 32 + m31;                 // local pixel 0..255 (248 valid)
    int r = (px >= 62) + (px >= 124) + (px >= 186) + (px >= 248);
    if (r > 3) r = 3;
    int wcol = px - r * 62;
    if (wcol > 61) wcol = 61;
    int orow = hg * 4 + r;
    bool valid = (px < 248) && (orow < 62);
    // lane base byte addr in xs: ((r*8 + khalf)*64 + wcol) * 16
    const char* lbase = (const char*)xs + (((r * 8 + khalf) * 64 + wcol) << 4);

    f32x16 acc0, acc1;
#pragma unroll
    for (int q = 0; q < 16; ++q) { acc0[q] = 0.f; acc1[q] = 0.f; }

#pragma unroll
    for (int tap = 0; tap < 9; ++tap) {
      int kh = tap / 3, kw = tap % 3;
#pragma unroll
      for (int k4 = 0; k4 < 4; ++k4) {
        bf16x8 Bf = *(const bf16x8*)(lbase + kh * 8192 + k4 * 2048 + kw * 16);
        int idx = tap * 4 + k4;
        if (idx & 1) acc1 = __builtin_amdgcn_mfma_f32_32x32x16_bf16(Wf[idx], Bf, acc1, 0, 0, 0);
        else         acc0 = __builtin_amdgcn_mfma_f32_32x32x16_bf16(Wf[idx], Bf, acc0, 0, 0, 0);
      }
    }
    if (valid) {
      size_t pix = ((size_t)b * HO + orow) * WO + wcol;
      // C/D layout 32x32: col=lane&31, row=(reg&3)+8*(reg>>2)+4*khalf
      float* up = u0 + pix * COUT + wv * 32 + khalf * 4;
#pragma unroll
      for (int g4 = 0; g4 < 4; ++g4) {
        f32x4 v;
#pragma unroll
        for (int q = 0; q < 4; ++q) v[q] = acc0[g4 * 4 + q] + acc1[g4 * 4 + q];
        *(f32x4*)&up[g4 * 8] = v;
      }
    }
  }
}

// ---------------------------------------------------------------------------
// iterate: 14 undamped Picard steps, fully on-chip.
//   a_{k+1} = relu((u0 - thr) - Wr * a_k),  a_0 = relu(u0 - thr)
// 512 threads = 8 waves; wave owns M=128 (all channels) x N=16 pixels.
// Wr A-frags live in 128 VGPRs; only a (bf16) round-trips through LDS.
// No barriers: each wave reads/writes only its own 16 LDS rows.
// ---------------------------------------------------------------------------
__global__ __launch_bounds__(512, 2) void iterate_kernel(
    const float* __restrict__ u0, const __bf16* __restrict__ wr,
    const float* __restrict__ thr, float* __restrict__ out) {
  __shared__ __align__(16) __bf16 a_s[128][136];
  int tid = threadIdx.x;
  int lane = tid & 63, wv = tid >> 6;
  int l15 = lane & 15, quad = lane >> 4;
  int nloc = wv * 16 + l15;                 // this lane's pixel (col)
  size_t p = (size_t)blockIdx.x * 128 + nloc;
  int pb = (int)(p / (HO * WO));            // batch  (for NCHW store)
  int pr = (int)(p % (HO * WO));            // h*62+w

  // Wr A-fragments (held in registers for the whole kernel): 8 mt x 4 kt
  bf16x8 Af[8][4];
#pragma unroll
  for (int mt = 0; mt < 8; ++mt) {
    int m = mt * 16 + l15;
#pragma unroll
    for (int kt = 0; kt < 4; ++kt)
      Af[mt][kt] = *(const bf16x8*)&wr[(size_t)m * COUT + kt * 32 + quad * 8];
  }
  // u0 fragments (C-layout), threshold folded in once
  f32x4 u0f[8];
#pragma unroll
  for (int mt = 0; mt < 8; ++mt) {
    f32x4 u = *(const f32x4*)&u0[p * COUT + mt * 16 + quad * 4];
    f32x4 t = *(const f32x4*)&thr[mt * 16 + quad * 4];
    u0f[mt] = u - t;
  }
  // a_0 = relu(u0 - thr) -> LDS (bf16), C-layout positions
#pragma unroll
  for (int mt = 0; mt < 8; ++mt) {
    bf16x4 pk;
    pk[0] = (__bf16)fmaxf(u0f[mt][0], 0.f);
    pk[1] = (__bf16)fmaxf(u0f[mt][1], 0.f);
    pk[2] = (__bf16)fmaxf(u0f[mt][2], 0.f);
    pk[3] = (__bf16)fmaxf(u0f[mt][3], 0.f);
    *(bf16x4*)&a_s[nloc][mt * 16 + quad * 4] = pk;
  }
#pragma unroll 1
  for (int it = 0; it < NITER; ++it) {
    bf16x8 Bf[4];
#pragma unroll
    for (int kt = 0; kt < 4; ++kt)
      Bf[kt] = *(const bf16x8*)&a_s[nloc][kt * 32 + quad * 8];
#pragma unroll
    for (int mt = 0; mt < 8; ++mt) {
      f32x4 acc = (f32x4){0.f, 0.f, 0.f, 0.f};
#pragma unroll
      for (int kt = 0; kt < 4; ++kt)
        acc = __builtin_amdgcn_mfma_f32_16x16x32_bf16(Af[mt][kt], Bf[kt], acc, 0, 0, 0);
      f32x4 a = u0f[mt] - acc;
      bf16x4 pk;
      pk[0] = (__bf16)fmaxf(a[0], 0.f);
      pk[1] = (__bf16)fmaxf(a[1], 0.f);
      pk[2] = (__bf16)fmaxf(a[2], 0.f);
      pk[3] = (__bf16)fmaxf(a[3], 0.f);
      *(bf16x4*)&a_s[nloc][mt * 16 + quad * 4] = pk;
    }
  }
  // final matvec -> a (fp32) -> NCHW global store
  {
    bf16x8 Bf[4];
#pragma unroll
    for (int kt = 0; kt < 4; ++kt)
      Bf[kt] = *(const bf16x8*)&a_s[nloc][kt * 32 + quad * 8];
#pragma unroll
    for (int mt = 0; mt < 8; ++mt) {
      f32x4 acc = (f32x4){0.f, 0.f, 0.f, 0.f};
#pragma unroll
      for (int kt = 0; kt < 4; ++kt)
        acc = __builtin_amdgcn_mfma_f32_16x16x32_bf16(Af[mt][kt], Bf[kt], acc, 0, 0, 0);
      f32x4 a = u0f[mt] - acc;
#pragma unroll
      for (int r = 0; r < 4; ++r) {
        size_t ob = ((size_t)pb * COUT + mt * 16 + quad * 4 + r) * (HO * WO) + pr;
        out[ob] = fmaxf(a[r], 0.f);
      }
    }
  }
}

// ---------------------------------------------------------------------------
extern "C" void kernel_launch(void* const* d_in, const int* in_sizes, int n_in,
                              void* d_out, int out_size, void* d_ws, size_t ws_size,
                              hipStream_t stream) {
  const float* x    = (const float*)d_in[0];   // (64,64,64,64)
  const float* wff  = (const float*)d_in[1];   // (128,64,3,3)
  const float* wrec = (const float*)d_in[2];   // (128,128,1,1)
  const float* thr  = (const float*)d_in[3];   // (128,)
  float* out = (float*)d_out;                  // (64,128,62,62)

  char* ws = (char*)d_ws;
  size_t off = 0;
  float*  u0 = (float*)(ws + off);  off += (size_t)NPIX * COUT * 4;          // 126 MB
  __bf16* xh = (__bf16*)(ws + off); off += (size_t)B_ * HIN * WIN * CIN * 2; // 33.6 MB
  __bf16* wt = (__bf16*)(ws + off); off += (size_t)9 * COUT * CIN * 2;       // 147 KB
  __bf16* wr = (__bf16*)(ws + off); off += (size_t)COUT * COUT * 2;          // 32 KB

  prep_w_kernel<<<352, 256, 0, stream>>>(wff, wrec, wt, wr);
  prep_x_kernel<<<B_ * HIN, 256, 0, stream>>>(x, xh);
  conv_kernel<<<dim3(16, B_), 256, 0, stream>>>(xh, wt, u0);
  iterate_kernel<<<NPIX / 128, 512, 0, stream>>>(u0, wr, thr, out);
}